// Round 17
// baseline (1040.823 us; speedup 1.0000x reference)
//
#include <hip/hip_runtime.h>
#include <math.h>

// Problem constants: B=16384 samples, DIM=64, WIDTH=256, DD=64, C2=16
#define SB 16      // samples per workgroup

// ws layout (float offsets)
#define OFF_W0T  0            // 5 x (64x256) (fallback k2_mf only)
#define OFF_W1T  81920        // 5 x (256x256) (fallback k2_mf only)
#define OFF_W2PT 409600       // unused on mf path
#define OFF_W2CT 925696
#define OFF_W2BT 1187840
#define OFF_DE   2236416      // 16384x64
#define OFF_DS   3284992      // 16384x64
#define WS_FLOATS 4337600
#define NPACK  1048576        // W2B packs
#define NPACKC 262144         // W2C packs
#define NPACKP 524288         // W2P packs (padded 2048)
#define WS3_FLOATS (WS_FLOATS + NPACK + NPACKC + NPACKP)
#define NK1 327680            // k1 packs
#define WS4_FLOATS (WS3_FLOATS + NK1)
#define NK3F 163840           // k3 forward packs (fC, fB)
#define WS5_FLOATS (WS4_FLOATS + NK3F)
#define NK2F 81920            // k2 forward packs (pA)
#define WS6_FLOATS (WS5_FLOATS + NK2F)

typedef __attribute__((ext_vector_type(8))) short bf16x8;
typedef __attribute__((ext_vector_type(4))) float f32x4;

__device__ __forceinline__ float4 f4fma(float a, float4 w, float4 c) {
    c.x = fmaf(a, w.x, c.x); c.y = fmaf(a, w.y, c.y);
    c.z = fmaf(a, w.z, c.z); c.w = fmaf(a, w.w, c.w);
    return c;
}

__device__ __forceinline__ float4 tanh4b(float4 a, float b) {
    return make_float4(tanhf(a.x + b), tanhf(a.y + b), tanhf(a.z + b), tanhf(a.w + b));
}

// fp32 -> bf16 hi (RNE) + bf16 lo (RNE of remainder)
__device__ __forceinline__ void bf16split(float x, unsigned short& hi, unsigned short& lo) {
    unsigned b = __float_as_uint(x);
    unsigned h = (b + 0x7FFFu + ((b >> 16) & 1u)) >> 16;
    hi = (unsigned short)h;
    float r = x - __uint_as_float(h << 16);
    unsigned rb = __float_as_uint(r);
    lo = (unsigned short)((rb + 0x7FFFu + ((rb >> 16) & 1u)) >> 16);
}

#define MFMA3(acc, Ah, Al, Bh, Bl)                                            \
    acc = __builtin_amdgcn_mfma_f32_16x16x32_bf16(Ah, Bh, acc, 0, 0, 0);      \
    acc = __builtin_amdgcn_mfma_f32_16x16x32_bf16(Al, Bh, acc, 0, 0, 0);      \
    acc = __builtin_amdgcn_mfma_f32_16x16x32_bf16(Ah, Bl, acc, 0, 0, 0);

// ---------------- merged transpose + bf16 fragment packing ----------------
__global__ __launch_bounds__(1024) void k_transpose_all(
    float* __restrict__ ws, int skipmid, int tofs,
    const float* __restrict__ W0a, const float* __restrict__ W0b, const float* __restrict__ W0c,
    const float* __restrict__ W0d, const float* __restrict__ W0e,
    const float* __restrict__ W1a, const float* __restrict__ W1b, const float* __restrict__ W1c,
    const float* __restrict__ W1d, const float* __restrict__ W1e,
    const float* __restrict__ W2p, const float* __restrict__ W2c, const float* __restrict__ W2b)
{
    int t = blockIdx.x * blockDim.x + threadIdx.x + tofs;
    if (t >= 2236416) {
        int e = t - 2236416;
        unsigned short* PK = (unsigned short*)(ws + WS_FLOATS);
        if (e < NPACK) {
            int j = e & 7, lane = (e >> 3) & 63, c = (e >> 9) & 7, tt = e >> 12;
            int k = c * 32 + ((lane >> 4) & 3) * 8 + j;
            int n = tt * 16 + (lane & 15);
            unsigned short hi, lo;
            bf16split(W2b[n * 256 + k], hi, lo);
            PK[e] = hi; PK[NPACK + e] = lo;
        } else if (e < NPACK + NPACKC) {
            int e2 = e - NPACK;
            unsigned short* PC = PK + 2 * NPACK;
            int j = e2 & 7, lane = (e2 >> 3) & 63, c = (e2 >> 9) & 7, tt = e2 >> 12;
            int k = c * 32 + ((lane >> 4) & 3) * 8 + j;
            int n = tt * 16 + (lane & 15);
            unsigned short hi, lo;
            bf16split(W2c[n * 256 + k], hi, lo);
            PC[e2] = hi; PC[NPACKC + e2] = lo;
        } else if (e < NPACK + NPACKC + NPACKP) {
            int e2 = e - NPACK - NPACKC;
            unsigned short* PP = PK + 2 * NPACK + 2 * NPACKC;
            int j = e2 & 7, lane = (e2 >> 3) & 63, c = (e2 >> 9) & 7, tt = e2 >> 12;
            int k = c * 32 + ((lane >> 4) & 3) * 8 + j;
            int n = tt * 16 + (lane & 15);
            float v = (n < 2016) ? W2p[n * 256 + k] : 0.f;
            unsigned short hi, lo;
            bf16split(v, hi, lo);
            PP[e2] = hi; PP[NPACKP + e2] = lo;
        } else if (e < NPACK + NPACKC + NPACKP + NK1) {
            int e2 = e - NPACK - NPACKC - NPACKP;
            unsigned short* PQ = PK + 2 * (NPACK + NPACKC + NPACKP);
            int net = e2 / 163840;
            int r = e2 - net * 163840;
            const float* W0m = net ? W0b : W0a;
            const float* W1m = net ? W1b : W1a;
            float v;
            if (r < 16384) {
                int j = r & 7, lane = (r >> 3) & 63, cb = (r >> 9) & 1, tt = r >> 10;
                int k = cb * 32 + ((lane >> 4) & 3) * 8 + j;
                int n = tt * 16 + (lane & 15);
                v = W0m[n * 64 + k];
            } else if (r < 81920) {
                int r2 = r - 16384;
                int j = r2 & 7, lane = (r2 >> 3) & 63, cb = (r2 >> 9) & 7, tt = r2 >> 12;
                int k = cb * 32 + ((lane >> 4) & 3) * 8 + j;
                int n = tt * 16 + (lane & 15);
                v = W1m[n * 256 + k];
            } else if (r < 147456) {
                int r2 = r - 81920;
                int j = r2 & 7, lane = (r2 >> 3) & 63, cb = (r2 >> 9) & 7, tt = r2 >> 12;
                int k = cb * 32 + ((lane >> 4) & 3) * 8 + j;
                int n = tt * 16 + (lane & 15);
                v = W1m[k * 256 + n];
            } else {
                int r2 = r - 147456;
                int j = r2 & 7, lane = (r2 >> 3) & 63, cb = (r2 >> 9) & 7, tt = r2 >> 12;
                int k = cb * 32 + ((lane >> 4) & 3) * 8 + j;
                int n = tt * 16 + (lane & 15);
                v = W0m[k * 64 + n];
            }
            unsigned short hi, lo;
            bf16split(v, hi, lo);
            PQ[e2] = hi; PQ[NK1 + e2] = lo;
        } else if (e < NPACK + NPACKC + NPACKP + NK1 + NK3F) {
            int e2 = e - NPACK - NPACKC - NPACKP - NK1;
            unsigned short* PQ = PK + 2 * (NPACK + NPACKC + NPACKP + NK1);
            int net = e2 / 81920;
            int r = e2 - net * 81920;
            const float* W0m = net ? W0e : W0d;
            const float* W1m = net ? W1e : W1d;
            float v;
            if (r < 16384) {
                int j = r & 7, lane = (r >> 3) & 63, cb = (r >> 9) & 1, tt = r >> 10;
                int k = cb * 32 + ((lane >> 4) & 3) * 8 + j;
                int n = tt * 16 + (lane & 15);
                v = W0m[n * 64 + k];
            } else {
                int r2 = r - 16384;
                int j = r2 & 7, lane = (r2 >> 3) & 63, cb = (r2 >> 9) & 7, tt = r2 >> 12;
                int k = cb * 32 + ((lane >> 4) & 3) * 8 + j;
                int n = tt * 16 + (lane & 15);
                v = W1m[n * 256 + k];
            }
            unsigned short hi, lo;
            bf16split(v, hi, lo);
            PQ[e2] = hi; PQ[NK3F + e2] = lo;
        } else if (e < NPACK + NPACKC + NPACKP + NK1 + NK3F + NK2F) {
            int r = e - NPACK - NPACKC - NPACKP - NK1 - NK3F;
            unsigned short* PQ = PK + 2 * (NPACK + NPACKC + NPACKP + NK1 + NK3F);
            float v;
            if (r < 16384) {
                int j = r & 7, lane = (r >> 3) & 63, cb = (r >> 9) & 1, tt = r >> 10;
                int k = cb * 32 + ((lane >> 4) & 3) * 8 + j;
                int n = tt * 16 + (lane & 15);
                v = W0c[n * 64 + k];
            } else {
                int r2 = r - 16384;
                int j = r2 & 7, lane = (r2 >> 3) & 63, cb = (r2 >> 9) & 7, tt = r2 >> 12;
                int k = cb * 32 + ((lane >> 4) & 3) * 8 + j;
                int n = tt * 16 + (lane & 15);
                v = W1c[n * 256 + k];
            }
            unsigned short hi, lo;
            bf16split(v, hi, lo);
            PQ[r] = hi; PQ[NK2F + r] = lo;
        }
        return;
    }
    if (skipmid && t >= 409600) return;
    const float* in;
    int o, R, C;
    float* out;
    if (t < 81920) {
        int m = t >> 14; o = t & 16383;
        const float* W0s[5] = {W0a, W0b, W0c, W0d, W0e};
        in = W0s[m]; out = ws + OFF_W0T + m * 16384; R = 256; C = 64;
    } else if (t < 409600) {
        int t2 = t - 81920;
        int m = t2 >> 16; o = t2 & 65535;
        const float* W1s[5] = {W1a, W1b, W1c, W1d, W1e};
        in = W1s[m]; out = ws + OFF_W1T + m * 65536; R = 256; C = 256;
    } else if (t < 925696) {
        o = t - 409600; in = W2p; out = ws + OFF_W2PT; R = 2016; C = 256;
    } else if (t < 1187840) {
        o = t - 925696; in = W2c; out = ws + OFF_W2CT; R = 1024; C = 256;
    } else {
        o = t - 1187840; in = W2b; out = ws + OFF_W2BT; R = 4096; C = 256;
    }
    int c = o / R, r = o - c * R;
    out[o] = in[r * C + c];
}

// ---------------- K1 mf: all four GEMM passes via split-bf16 MFMA ----------------
__global__ __launch_bounds__(1024, 2) void k1_grads_mf(
    const float* __restrict__ y, const float* __restrict__ ws,
    const float* __restrict__ b0E, const float* __restrict__ b1E, const float* __restrict__ w2E,
    const float* __restrict__ b0S, const float* __restrict__ b1S, const float* __restrict__ w2S,
    float* __restrict__ odE, float* __restrict__ odS)
{
    __shared__ float sH1f[4352];
    __shared__ unsigned short yAh[1024], yAl[1024];
    __shared__ unsigned short bAh[4096], bAl[4096];
    __shared__ unsigned short bBh[4096], bBl[4096];
    __shared__ float sPart[4352];

    const int tid = threadIdx.x;
    const int sbase = blockIdx.x * SB;
    const int wv = tid >> 6, l = tid & 63;

    {
        int s = tid >> 6, k = tid & 63;
        unsigned short hi, lo;
        bf16split(y[sbase * 64 + tid], hi, lo);
        int addr = ((k >> 5) * 64 + (s | (((k >> 3) & 3) << 4))) * 8 + (k & 7);
        yAh[addr] = hi; yAl[addr] = lo;
    }
    __syncthreads();

    const unsigned short* K1H = (const unsigned short*)(ws + WS3_FLOATS);
    const unsigned short* K1L = K1H + NK1;

    for (int m = 0; m < 2; ++m) {
        const float* b0 = m ? b0S : b0E;
        const float* b1 = m ? b1S : b1E;
        const float* w2 = m ? w2S : w2E;
        float* outg = m ? odS : odE;
        const int pbase = m * 163840;

        {
            const unsigned short* PH = K1H + pbase;
            const unsigned short* PL = K1L + pbase;
            f32x4 acc = {0.f, 0.f, 0.f, 0.f};
            #pragma unroll
            for (int cb = 0; cb < 2; ++cb) {
                bf16x8 Ah = *(const bf16x8*)(yAh + (cb * 64 + l) * 8);
                bf16x8 Al = *(const bf16x8*)(yAl + (cb * 64 + l) * 8);
                bf16x8 Bh = *(const bf16x8*)(PH + ((wv * 2 + cb) * 64 + l) * 8);
                bf16x8 Bl = *(const bf16x8*)(PL + ((wv * 2 + cb) * 64 + l) * 8);
                MFMA3(acc, Ah, Al, Bh, Bl);
            }
            int c = 16 * wv + (l & 15);
            float bb = b0[c];
            const int cblk = c >> 5, j0 = c & 7;
            const int lb2 = ((c >> 3) & 3) << 4;
            #pragma unroll
            for (int r = 0; r < 4; ++r) {
                int s = (l >> 4) * 4 + r;
                float h1 = tanhf(acc[r] + bb);
                sH1f[c * 17 + s] = h1;
                unsigned short hi, lo;
                bf16split(h1, hi, lo);
                int base = (cblk * 64 + (s | lb2)) * 8 + j0;
                bBh[base] = hi; bBl[base] = lo;
            }
        }
        __syncthreads();

        {
            const unsigned short* PH = K1H + pbase + 16384;
            const unsigned short* PL = K1L + pbase + 16384;
            f32x4 acc = {0.f, 0.f, 0.f, 0.f};
            #pragma unroll 1
            for (int cb = 0; cb < 8; ++cb) {
                bf16x8 Ah = *(const bf16x8*)(bBh + (cb * 64 + l) * 8);
                bf16x8 Al = *(const bf16x8*)(bBl + (cb * 64 + l) * 8);
                bf16x8 Bh = *(const bf16x8*)(PH + ((wv * 8 + cb) * 64 + l) * 8);
                bf16x8 Bl = *(const bf16x8*)(PL + ((wv * 8 + cb) * 64 + l) * 8);
                MFMA3(acc, Ah, Al, Bh, Bl);
            }
            int c = 16 * wv + (l & 15);
            float bb = b1[c], wvv = w2[c];
            const int cblk = c >> 5, j0 = c & 7;
            const int lb2 = ((c >> 3) & 3) << 4;
            #pragma unroll
            for (int r = 0; r < 4; ++r) {
                int s = (l >> 4) * 4 + r;
                float h2 = tanhf(acc[r] + bb);
                float g2 = (1.f - h2 * h2) * wvv;
                unsigned short hi, lo;
                bf16split(g2, hi, lo);
                int base = (cblk * 64 + (s | lb2)) * 8 + j0;
                bAh[base] = hi; bAl[base] = lo;
            }
        }
        __syncthreads();

        {
            const unsigned short* PH = K1H + pbase + 81920;
            const unsigned short* PL = K1L + pbase + 81920;
            f32x4 acc = {0.f, 0.f, 0.f, 0.f};
            #pragma unroll 1
            for (int cb = 0; cb < 8; ++cb) {
                bf16x8 Ah = *(const bf16x8*)(bAh + (cb * 64 + l) * 8);
                bf16x8 Al = *(const bf16x8*)(bAl + (cb * 64 + l) * 8);
                bf16x8 Bh = *(const bf16x8*)(PH + ((wv * 8 + cb) * 64 + l) * 8);
                bf16x8 Bl = *(const bf16x8*)(PL + ((wv * 8 + cb) * 64 + l) * 8);
                MFMA3(acc, Ah, Al, Bh, Bl);
            }
            int c = 16 * wv + (l & 15);
            const int cblk = c >> 5, j0 = c & 7;
            const int lb2 = ((c >> 3) & 3) << 4;
            #pragma unroll
            for (int r = 0; r < 4; ++r) {
                int s = (l >> 4) * 4 + r;
                float h1 = sH1f[c * 17 + s];
                float g1 = (1.f - h1 * h1) * acc[r];
                unsigned short hi, lo;
                bf16split(g1, hi, lo);
                int base = (cblk * 64 + (s | lb2)) * 8 + j0;
                bBh[base] = hi; bBl[base] = lo;
            }
        }
        __syncthreads();

        {
            const unsigned short* PH = K1H + pbase + 147456;
            const unsigned short* PL = K1L + pbase + 147456;
            const int t = wv & 3, kh = wv >> 2;
            f32x4 acc = {0.f, 0.f, 0.f, 0.f};
            #pragma unroll
            for (int q = 0; q < 2; ++q) {
                int cb = 2 * kh + q;
                bf16x8 Ah = *(const bf16x8*)(bBh + (cb * 64 + l) * 8);
                bf16x8 Al = *(const bf16x8*)(bBl + (cb * 64 + l) * 8);
                bf16x8 Bh = *(const bf16x8*)(PH + ((t * 8 + cb) * 64 + l) * 8);
                bf16x8 Bl = *(const bf16x8*)(PL + ((t * 8 + cb) * 64 + l) * 8);
                MFMA3(acc, Ah, Al, Bh, Bl);
            }
            #pragma unroll
            for (int r = 0; r < 4; ++r)
                sPart[(kh * 4 + t) * 272 + (l & 15) * 17 + ((l >> 4) * 4 + r)] = acc[r];
        }
        __syncthreads();
        {
            int s = tid >> 6, i = tid & 63;
            float v = 0.f;
            #pragma unroll
            for (int kh = 0; kh < 4; ++kh)
                v += sPart[(kh * 4 + (i >> 4)) * 272 + (i & 15) * 17 + s];
            outg[sbase * 64 + tid] = v;
        }
        __syncthreads();
    }
}

// ---------------- K2 mf (fallback): forwards fp32, a-GEMM MFMA ----------------
__global__ __launch_bounds__(1024, 4) void k2_poisson_mf(
    const float* __restrict__ y, const float* __restrict__ ws,
    const float* __restrict__ b0P, const float* __restrict__ b1P,
    float* __restrict__ dout)
{
    extern __shared__ float smem[];
    float* sa   = smem;
    unsigned short* sAh = (unsigned short*)(smem + 32384);
    unsigned short* sAl = (unsigned short*)(smem + 34432);
    float* sdE  = smem + 36480;
    float* sdS  = sdE + 1024;
    float* sH1T = sa;
    float* syT  = sa + 4096;

    const int tid = threadIdx.x;
    const int sbase = blockIdx.x * SB;
    const float* gdE = ws + OFF_DE;
    const float* gdS = ws + OFF_DS;

    {
        int s = tid >> 6, i = tid & 63;
        syT[i * 16 + s] = y[sbase * 64 + tid];
        sdE[tid] = gdE[sbase * 64 + tid];
        sdS[tid] = gdS[sbase * 64 + tid];
    }
    __syncthreads();

    const int c  = tid & 255;
    const int sg = tid >> 8;
    const int s4 = sg * 4;

    {
        const float* w0t = ws + OFF_W0T + 2 * 16384;
        float4 acc = {0, 0, 0, 0};
        #pragma unroll 4
        for (int k = 0; k < 64; ++k) {
            float w = w0t[k * 256 + c];
            float4 yv = *(const float4*)(syT + k * 16 + s4);
            acc = f4fma(w, yv, acc);
        }
        *(float4*)(sH1T + c * 16 + s4) = tanh4b(acc, b0P[c]);
    }
    __syncthreads();

    {
        const float* w1t = ws + OFF_W1T + 2 * 65536;
        float4 acc = {0, 0, 0, 0};
        #pragma unroll 4
        for (int k = 0; k < 256; ++k) {
            float w = w1t[k * 256 + c];
            float4 hv = *(const float4*)(sH1T + k * 16 + s4);
            acc = f4fma(w, hv, acc);
        }
        float4 h2 = tanh4b(acc, b1P[c]);
        const int cblk = c >> 5, j0 = c & 7;
        const int lbase = ((c >> 3) & 3) << 4;
        float va[4] = {h2.x, h2.y, h2.z, h2.w};
        #pragma unroll
        for (int q = 0; q < 4; ++q) {
            int lb = ((s4 + q) & 15) | lbase;
            int base = (cblk * 64 + lb) * 8 + j0;
            unsigned short hi, lo;
            bf16split(va[q], hi, lo);
            sAh[base] = hi;
            sAl[base] = lo;
        }
    }
    __syncthreads();

    {
        const unsigned short* PP = (const unsigned short*)(ws + WS_FLOATS) + 2 * NPACK + 2 * NPACKC;
        const unsigned short* PH = PP;
        const unsigned short* PL = PP + NPACKP;
        const int wv = tid >> 6, l = tid & 63;
        f32x4 accp[8];
        #pragma unroll
        for (int t0 = 0; t0 < 8; ++t0) accp[t0] = (f32x4){0.f, 0.f, 0.f, 0.f};
        #pragma unroll 1
        for (int cb = 0; cb < 8; ++cb) {
            bf16x8 Ah = *(const bf16x8*)(sAh + (cb * 64 + l) * 8);
            bf16x8 Al = *(const bf16x8*)(sAl + (cb * 64 + l) * 8);
            #pragma unroll
            for (int t0 = 0; t0 < 8; ++t0) {
                int t = 8 * wv + t0;
                bf16x8 Bh = *(const bf16x8*)(PH + ((t * 8 + cb) * 64 + l) * 8);
                bf16x8 Bl = *(const bf16x8*)(PL + ((t * 8 + cb) * 64 + l) * 8);
                MFMA3(accp[t0], Ah, Al, Bh, Bl);
            }
        }
        #pragma unroll
        for (int t0 = 0; t0 < 8; ++t0) {
            int n = (8 * wv + t0) * 16 + (l & 15);
            if (n < 2016) {
                #pragma unroll
                for (int r = 0; r < 4; ++r)
                    sa[((l >> 4) * 4 + r) * 2024 + n] = accp[t0][r];
            }
        }
    }
    __syncthreads();

    {
        const int s = tid >> 6;
        const int i = tid & 63;
        const int ib = i * (i - 1) / 2;
        const float* ap = sa + s * 2024;
        const float* dep = sdE + s * 64;
        const float* dsp = sdS + s * 64;

        float adE = 0.f, adS = 0.f;
        int trij = 0;
        #pragma unroll 4
        for (int j = 0; j < 64; ++j) {
            int t = (j < i) ? (ib + j) : (trij + i);
            float sel = (j < i) ? 1.f : ((j == i) ? 0.f : -1.f);
            float cc = sel * ap[t];
            adE = fmaf(cc, dep[j], adE);
            adS = fmaf(cc, dsp[j], adS);
            trij += j;
        }

        float de = dep[i], dsv = dsp[i];
        float p0 = de * adS;
        float p1 = de * dsv;
        float p2 = dsv * dsv;
        #pragma unroll
        for (int m = 1; m <= 32; m <<= 1) {
            p0 += __shfl_xor(p0, m);
            p1 += __shfl_xor(p1, m);
            p2 += __shfl_xor(p2, m);
        }
        float inv = 1.f / p2;
        dout[sbase * 64 + tid] = adE + (p0 * dsv - p1 * adS) * inv;
    }
}

// ---------------- K2 mf2: forwards AND a-GEMM via split-bf16 MFMA ----------------
__global__ __launch_bounds__(1024, 4) void k2_poisson_mf2(
    const float* __restrict__ y, const float* __restrict__ ws,
    const float* __restrict__ b0P, const float* __restrict__ b1P,
    float* __restrict__ dout)
{
    extern __shared__ float smem[];
    float* sa   = smem;                                   // 16 x 2024
    unsigned short* yAh = (unsigned short*)(smem);
    unsigned short* yAl = (unsigned short*)(smem + 512);
    unsigned short* h1H = (unsigned short*)(smem + 1024);
    unsigned short* h1L = (unsigned short*)(smem + 3072);
    unsigned short* sAh = (unsigned short*)(smem + 32384);
    unsigned short* sAl = (unsigned short*)(smem + 34432);
    float* sdE  = smem + 36480;
    float* sdS  = sdE + 1024;

    const int tid = threadIdx.x;
    const int sbase = blockIdx.x * SB;
    const float* gdE = ws + OFF_DE;
    const float* gdS = ws + OFF_DS;

    {
        int s = tid >> 6, k = tid & 63;
        unsigned short hi, lo;
        bf16split(y[sbase * 64 + tid], hi, lo);
        int addr = ((k >> 5) * 64 + (s | (((k >> 3) & 3) << 4))) * 8 + (k & 7);
        yAh[addr] = hi; yAl[addr] = lo;
        sdE[tid] = gdE[sbase * 64 + tid];
        sdS[tid] = gdS[sbase * 64 + tid];
    }
    __syncthreads();

    const int wv = tid >> 6, l = tid & 63;
    const unsigned short* F2H = (const unsigned short*)(ws + WS5_FLOATS);
    const unsigned short* F2L = F2H + NK2F;

    {
        f32x4 acc = {0.f, 0.f, 0.f, 0.f};
        #pragma unroll
        for (int cb = 0; cb < 2; ++cb) {
            bf16x8 Ah = *(const bf16x8*)(yAh + (cb * 64 + l) * 8);
            bf16x8 Al = *(const bf16x8*)(yAl + (cb * 64 + l) * 8);
            bf16x8 Bh = *(const bf16x8*)(F2H + ((wv * 2 + cb) * 64 + l) * 8);
            bf16x8 Bl = *(const bf16x8*)(F2L + ((wv * 2 + cb) * 64 + l) * 8);
            MFMA3(acc, Ah, Al, Bh, Bl);
        }
        int c = 16 * wv + (l & 15);
        float bb = b0P[c];
        const int cblk = c >> 5, j0 = c & 7;
        const int lb2 = ((c >> 3) & 3) << 4;
        #pragma unroll
        for (int r = 0; r < 4; ++r) {
            int s = (l >> 4) * 4 + r;
            float h1 = tanhf(acc[r] + bb);
            unsigned short hi, lo;
            bf16split(h1, hi, lo);
            int base = (cblk * 64 + (s | lb2)) * 8 + j0;
            h1H[base] = hi; h1L[base] = lo;
        }
    }
    __syncthreads();

    {
        f32x4 acc = {0.f, 0.f, 0.f, 0.f};
        #pragma unroll 1
        for (int cb = 0; cb < 8; ++cb) {
            bf16x8 Ah = *(const bf16x8*)(h1H + (cb * 64 + l) * 8);
            bf16x8 Al = *(const bf16x8*)(h1L + (cb * 64 + l) * 8);
            bf16x8 Bh = *(const bf16x8*)(F2H + 16384 + ((wv * 8 + cb) * 64 + l) * 8);
            bf16x8 Bl = *(const bf16x8*)(F2L + 16384 + ((wv * 8 + cb) * 64 + l) * 8);
            MFMA3(acc, Ah, Al, Bh, Bl);
        }
        int c = 16 * wv + (l & 15);
        float bb = b1P[c];
        const int cblk = c >> 5, j0 = c & 7;
        const int lb2 = ((c >> 3) & 3) << 4;
        #pragma unroll
        for (int r = 0; r < 4; ++r) {
            int s = (l >> 4) * 4 + r;
            float h2 = tanhf(acc[r] + bb);
            unsigned short hi, lo;
            bf16split(h2, hi, lo);
            int base = (cblk * 64 + (s | lb2)) * 8 + j0;
            sAh[base] = hi; sAl[base] = lo;
        }
    }
    __syncthreads();

    {
        const unsigned short* PP = (const unsigned short*)(ws + WS_FLOATS) + 2 * NPACK + 2 * NPACKC;
        const unsigned short* PH = PP;
        const unsigned short* PL = PP + NPACKP;
        f32x4 accp[8];
        #pragma unroll
        for (int t0 = 0; t0 < 8; ++t0) accp[t0] = (f32x4){0.f, 0.f, 0.f, 0.f};
        #pragma unroll 1
        for (int cb = 0; cb < 8; ++cb) {
            bf16x8 Ah = *(const bf16x8*)(sAh + (cb * 64 + l) * 8);
            bf16x8 Al = *(const bf16x8*)(sAl + (cb * 64 + l) * 8);
            #pragma unroll
            for (int t0 = 0; t0 < 8; ++t0) {
                int t = 8 * wv + t0;
                bf16x8 Bh = *(const bf16x8*)(PH + ((t * 8 + cb) * 64 + l) * 8);
                bf16x8 Bl = *(const bf16x8*)(PL + ((t * 8 + cb) * 64 + l) * 8);
                MFMA3(accp[t0], Ah, Al, Bh, Bl);
            }
        }
        #pragma unroll
        for (int t0 = 0; t0 < 8; ++t0) {
            int n = (8 * wv + t0) * 16 + (l & 15);
            if (n < 2016) {
                #pragma unroll
                for (int r = 0; r < 4; ++r)
                    sa[((l >> 4) * 4 + r) * 2024 + n] = accp[t0][r];
            }
        }
    }
    __syncthreads();

    {
        const int s = tid >> 6;
        const int i = tid & 63;
        const int ib = i * (i - 1) / 2;
        const float* ap = sa + s * 2024;
        const float* dep = sdE + s * 64;
        const float* dsp = sdS + s * 64;

        float adE = 0.f, adS = 0.f;
        int trij = 0;
        #pragma unroll 4
        for (int j = 0; j < 64; ++j) {
            int t = (j < i) ? (ib + j) : (trij + i);
            float sel = (j < i) ? 1.f : ((j == i) ? 0.f : -1.f);
            float cc = sel * ap[t];
            adE = fmaf(cc, dep[j], adE);
            adS = fmaf(cc, dsp[j], adS);
            trij += j;
        }

        float de = dep[i], dsv = dsp[i];
        float p0 = de * adS;
        float p1 = de * dsv;
        float p2 = dsv * dsv;
        #pragma unroll
        for (int m = 1; m <= 32; m <<= 1) {
            p0 += __shfl_xor(p0, m);
            p1 += __shfl_xor(p1, m);
            p2 += __shfl_xor(p2, m);
        }
        float inv = 1.f / p2;
        dout[sbase * 64 + tid] = adE + (p0 * dsv - p1 * adS) * inv;
    }
}

// ---------------- K3 mf4: all-MFMA + sC-free epilogue (C kept in accc regs) ----------------
// LDS (floats): yA@0..1024 | H2 packs@1024..9216 |
//   union{ H1 packs@9216..17408 ; post-L1: sBdE@9216 sBdS@10240 sv@11264 sq@12288 sr@13312(+256) }
//   sdE@17408 sdS@18432 sScal@19456(+64). Total 19520 f = 78,080 B -> 2 blocks/CU.
__global__ __launch_bounds__(1024, 8) void k3_friction_mf4(
    const float* __restrict__ y, const float* __restrict__ ws,
    const float* __restrict__ b0C, const float* __restrict__ b1C,
    const float* __restrict__ b0B, const float* __restrict__ b1B,
    float* __restrict__ dout)
{
    extern __shared__ float smem[];
    unsigned short* yAh = (unsigned short*)(smem);
    unsigned short* yAl = (unsigned short*)(smem + 512);
    unsigned short* sAhc = (unsigned short*)(smem + 1024);
    unsigned short* sAlc = (unsigned short*)(smem + 3072);
    unsigned short* sAhb = (unsigned short*)(smem + 5120);
    unsigned short* sAlb = (unsigned short*)(smem + 7168);
    unsigned short* h1ch = (unsigned short*)(smem + 9216);
    unsigned short* h1cl = (unsigned short*)(smem + 11264);
    unsigned short* h1bh = (unsigned short*)(smem + 13312);
    unsigned short* h1bl = (unsigned short*)(smem + 15360);
    float* sBdE = smem + 9216;     // union with H1 packs (dead post-L1)
    float* sBdS = smem + 10240;
    float* sv   = smem + 11264;
    float* sq   = smem + 12288;
    float* sr   = smem + 13312;    // 256 floats
    float* sdE  = smem + 17408;
    float* sdS  = smem + 18432;
    float* sScal= smem + 19456;    // 64 floats

    const int tid = threadIdx.x;
    const int sbase = blockIdx.x * SB;
    const float* gdE = ws + OFF_DE;
    const float* gdS = ws + OFF_DS;

    {
        int s = tid >> 6, k = tid & 63;
        unsigned short hi, lo;
        bf16split(y[sbase * 64 + tid], hi, lo);
        int addr = ((k >> 5) * 64 + (s | (((k >> 3) & 3) << 4))) * 8 + (k & 7);
        yAh[addr] = hi; yAl[addr] = lo;
        sdE[tid] = gdE[sbase * 64 + tid];
        sdS[tid] = gdS[sbase * 64 + tid];
    }
    if (tid < 64) sScal[tid] = 0.f;
    __syncthreads();

    {
        int s = tid >> 6;
        float de = sdE[tid];
        unsafeAtomicAdd(&sScal[s * 4 + 0], de * de);
        unsafeAtomicAdd(&sScal[s * 4 + 1], de * sdS[tid]);
    }

    const int wv = tid >> 6;
    const int l  = tid & 63;
    const int netw = wv >> 3;
    const int tb   = wv & 7;
    const float* b0v = netw ? b0B : b0C;
    const float* b1v = netw ? b1B : b1C;
    unsigned short* h1H = netw ? h1bh : h1ch;
    unsigned short* h1L = netw ? h1bl : h1cl;
    unsigned short* h2H = netw ? sAhb : sAhc;
    unsigned short* h2L = netw ? sAlb : sAlc;

    const unsigned short* F3H = (const unsigned short*)(ws + WS4_FLOATS);
    const unsigned short* F3L = F3H + NK3F;

    // L0 (MFMA)
    #pragma unroll
    for (int jj = 0; jj < 2; ++jj) {
        int t = tb + 8 * jj;
        f32x4 acc = {0.f, 0.f, 0.f, 0.f};
        #pragma unroll
        for (int cb = 0; cb < 2; ++cb) {
            bf16x8 Ah = *(const bf16x8*)(yAh + (cb * 64 + l) * 8);
            bf16x8 Al = *(const bf16x8*)(yAl + (cb * 64 + l) * 8);
            const unsigned short* bh = F3H + netw * 81920 + ((t * 2 + cb) * 64 + l) * 8;
            const unsigned short* bl = F3L + netw * 81920 + ((t * 2 + cb) * 64 + l) * 8;
            bf16x8 Bh = *(const bf16x8*)(bh);
            bf16x8 Bl = *(const bf16x8*)(bl);
            MFMA3(acc, Ah, Al, Bh, Bl);
        }
        int c = 16 * t + (l & 15);
        float bb = b0v[c];
        const int cblk = c >> 5, j0 = c & 7;
        const int lb2 = ((c >> 3) & 3) << 4;
        #pragma unroll
        for (int r = 0; r < 4; ++r) {
            int s = (l >> 4) * 4 + r;
            float h1 = tanhf(acc[r] + bb);
            unsigned short hi, lo;
            bf16split(h1, hi, lo);
            int base = (cblk * 64 + (s | lb2)) * 8 + j0;
            h1H[base] = hi; h1L[base] = lo;
        }
    }
    __syncthreads();

    // L1 (MFMA)
    #pragma unroll
    for (int jj = 0; jj < 2; ++jj) {
        int t = tb + 8 * jj;
        f32x4 acc = {0.f, 0.f, 0.f, 0.f};
        #pragma unroll 1
        for (int cb = 0; cb < 8; ++cb) {
            bf16x8 Ah = *(const bf16x8*)(h1H + (cb * 64 + l) * 8);
            bf16x8 Al = *(const bf16x8*)(h1L + (cb * 64 + l) * 8);
            const unsigned short* bh = F3H + netw * 81920 + 16384 + ((t * 8 + cb) * 64 + l) * 8;
            const unsigned short* bl = F3L + netw * 81920 + 16384 + ((t * 8 + cb) * 64 + l) * 8;
            bf16x8 Bh = *(const bf16x8*)(bh);
            bf16x8 Bl = *(const bf16x8*)(bl);
            MFMA3(acc, Ah, Al, Bh, Bl);
        }
        int c = 16 * t + (l & 15);
        float bb = b1v[c];
        const int cblk = c >> 5, j0 = c & 7;
        const int lb2 = ((c >> 3) & 3) << 4;
        #pragma unroll
        for (int r = 0; r < 4; ++r) {
            int s = (l >> 4) * 4 + r;
            float h2 = tanhf(acc[r] + bb);
            unsigned short hi, lo;
            bf16split(h2, hi, lo);
            int base = (cblk * 64 + (s | lb2)) * 8 + j0;
            h2H[base] = hi; h2L[base] = lo;
        }
    }
    __syncthreads();   // H1 packs dead; union region writable

    // C head via MFMA: wave owns n-tiles 4wv..4wv+3; C stays in accc registers
    f32x4 accc[4];
    #pragma unroll
    for (int t0 = 0; t0 < 4; ++t0) accc[t0] = (f32x4){0.f, 0.f, 0.f, 0.f};
    {
        const unsigned short* PC = (const unsigned short*)(ws + WS_FLOATS) + 2 * NPACK;
        const unsigned short* CH = PC;
        const unsigned short* CL = PC + NPACKC;
        #pragma unroll 1
        for (int cb = 0; cb < 8; ++cb) {
            bf16x8 Ah = *(const bf16x8*)(sAhc + (cb * 64 + l) * 8);
            bf16x8 Al = *(const bf16x8*)(sAlc + (cb * 64 + l) * 8);
            #pragma unroll
            for (int t0 = 0; t0 < 4; ++t0) {
                int t = 4 * wv + t0;
                bf16x8 Bh = *(const bf16x8*)(CH + ((t * 8 + cb) * 64 + l) * 8);
                bf16x8 Bl = *(const bf16x8*)(CL + ((t * 8 + cb) * 64 + l) * 8);
                MFMA3(accc[t0], Ah, Al, Bh, Bl);
            }
        }
    }

    // Bm via MFMA: wave owns n-tiles 16wv..16wv+15
    f32x4 acc[16];
    #pragma unroll
    for (int t0 = 0; t0 < 16; ++t0) acc[t0] = (f32x4){0.f, 0.f, 0.f, 0.f};
    {
        const unsigned short* BH = (const unsigned short*)(ws + WS_FLOATS);
        const unsigned short* BL = BH + NPACK;
        #pragma unroll 1
        for (int cb = 0; cb < 8; ++cb) {
            bf16x8 Ah = *(const bf16x8*)(sAhb + (cb * 64 + l) * 8);
            bf16x8 Al = *(const bf16x8*)(sAlb + (cb * 64 + l) * 8);
            const unsigned short* bh = BH + ((wv * 16 * 8 + cb) * 64 + l) * 8;
            const unsigned short* bl = BL + ((wv * 16 * 8 + cb) * 64 + l) * 8;
            #pragma unroll
            for (int t0 = 0; t0 < 16; ++t0) {
                bf16x8 Bh = *(const bf16x8*)(bh + t0 * 4096);
                bf16x8 Bl = *(const bf16x8*)(bl + t0 * 4096);
                MFMA3(acc[t0], Ah, Al, Bh, Bl);
            }
        }
    }
    // dots -> sBdE/sBdS (written into union region; H1 packs dead)
    #pragma unroll
    for (int g = 0; g < 4; ++g) {
        float pd[4] = {0, 0, 0, 0}, ps[4] = {0, 0, 0, 0};
        #pragma unroll
        for (int tt = 0; tt < 4; ++tt) {
            int i = 16 * tt + (l & 15);
            #pragma unroll
            for (int r = 0; r < 4; ++r) {
                int s = (l >> 4) * 4 + r;
                float d = acc[g * 4 + tt][r];
                pd[r] = fmaf(d, sdE[s * 64 + i], pd[r]);
                ps[r] = fmaf(d, sdS[s * 64 + i], ps[r]);
            }
        }
        #pragma unroll
        for (int m = 1; m <= 8; m <<= 1) {
            #pragma unroll
            for (int r = 0; r < 4; ++r) {
                pd[r] += __shfl_xor(pd[r], m);
                ps[r] += __shfl_xor(ps[r], m);
            }
        }
        if ((l & 15) == 0) {
            int kpr = 4 * wv + g;
            #pragma unroll
            for (int r = 0; r < 4; ++r) {
                int s = (l >> 4) * 4 + r;
                sBdE[s * 64 + kpr] = pd[r];
                sBdS[s * 64 + kpr] = ps[r];
            }
        }
    }
    __syncthreads();

    // v = BdS - beta*BdE; zero sr
    {
        int s = tid >> 6;
        float beta = sScal[s * 4 + 1] / sScal[s * 4 + 0];
        sv[tid] = sBdS[tid] - beta * sBdE[tid];
        if (tid < 256) sr[tid] = 0.f;
    }
    __syncthreads();
    {
        int s = tid >> 6;
        unsafeAtomicAdd(&sScal[s * 4 + 2], sdE[tid] * sv[tid]);
    }
    __syncthreads();

    // pass2: q = Bm @ v from acc registers
    #pragma unroll
    for (int g = 0; g < 4; ++g) {
        float pq[4] = {0, 0, 0, 0};
        #pragma unroll
        for (int tt = 0; tt < 4; ++tt) {
            int i = 16 * tt + (l & 15);
            #pragma unroll
            for (int r = 0; r < 4; ++r) {
                int s = (l >> 4) * 4 + r;
                pq[r] = fmaf(acc[g * 4 + tt][r], sv[s * 64 + i], pq[r]);
            }
        }
        #pragma unroll
        for (int m = 1; m <= 8; m <<= 1) {
            #pragma unroll
            for (int r = 0; r < 4; ++r) pq[r] += __shfl_xor(pq[r], m);
        }
        if ((l & 15) == 0) {
            int kpr = 4 * wv + g;
            #pragma unroll
            for (int r = 0; r < 4; ++r) sq[((l >> 4) * 4 + r) * 64 + kpr] = pq[r];
        }
    }
    __syncthreads();

    // r-phase: r[s][m] += C[s][k][m] * (q[s][k] - gamma_s*BdE[s][k]) from accc regs
    #pragma unroll
    for (int t0 = 0; t0 < 4; ++t0) {
        int k = 4 * wv + t0;
        #pragma unroll
        for (int r = 0; r < 4; ++r) {
            int s = (l >> 4) * 4 + r;
            float gamma = sScal[s * 4 + 2] / sScal[s * 4 + 0];
            float w = sq[s * 64 + k] - gamma * sBdE[s * 64 + k];
            unsafeAtomicAdd(&sr[s * 16 + (l & 15)], accc[t0][r] * w);
        }
    }
    __syncthreads();

    // out-phase: out[s][k] += sum_m C[s][k][m]*r[s][m]; reduce over m-subgroup
    #pragma unroll
    for (int t0 = 0; t0 < 4; ++t0) {
        int k = 4 * wv + t0;
        float po[4];
        #pragma unroll
        for (int r = 0; r < 4; ++r) {
            int s = (l >> 4) * 4 + r;
            po[r] = accc[t0][r] * sr[s * 16 + (l & 15)];
        }
        #pragma unroll
        for (int m = 1; m <= 8; m <<= 1) {
            #pragma unroll
            for (int r = 0; r < 4; ++r) po[r] += __shfl_xor(po[r], m);
        }
        if ((l & 15) == 0) {
            #pragma unroll
            for (int r = 0; r < 4; ++r) {
                int s = (l >> 4) * 4 + r;
                int gi = sbase * 64 + s * 64 + k;
                dout[gi] = dout[gi] + po[r];
            }
        }
    }
}

extern "C" void kernel_launch(void* const* d_in, const int* in_sizes, int n_in,
                              void* d_out, int out_size, void* d_ws, size_t ws_size,
                              hipStream_t stream)
{
    (void)in_sizes; (void)n_in; (void)out_size;
    const float* y = (const float*)d_in[1];
    const float* W0[5]; const float* b0[5]; const float* W1[5]; const float* b1[5]; const float* W2[5];
    for (int m = 0; m < 5; ++m) {
        int base = 2 + m * 5;
        W0[m] = (const float*)d_in[base + 0];
        b0[m] = (const float*)d_in[base + 1];
        W1[m] = (const float*)d_in[base + 2];
        b1[m] = (const float*)d_in[base + 3];
        W2[m] = (const float*)d_in[base + 4];
    }
    float* ws = (float*)d_ws;
    float* dout = (float*)d_out;
    if (ws_size < (size_t)WS5_FLOATS * sizeof(float)) return;
    const bool big4 = ws_size >= (size_t)WS6_FLOATS * sizeof(float);

    if (big4) {
        // mf path reads only the pack segments; skip all fp32 transposes
        const int npack_all = NPACK + NPACKC + NPACKP + NK1 + NK3F + NK2F;
        hipLaunchKernelGGL(k_transpose_all, dim3((npack_all + 1023) / 1024), dim3(1024), 0, stream,
                           ws, 1, 2236416,
                           W0[0], W0[1], W0[2], W0[3], W0[4],
                           W1[0], W1[1], W1[2], W1[3], W1[4],
                           W2[2], W2[3], W2[4]);
    } else {
        const int ntr = 2236416 + NPACK + NPACKC + NPACKP + NK1 + NK3F;
        hipLaunchKernelGGL(k_transpose_all, dim3((ntr + 1023) / 1024), dim3(1024), 0, stream,
                           ws, 1, 0,
                           W0[0], W0[1], W0[2], W0[3], W0[4],
                           W1[0], W1[1], W1[2], W1[3], W1[4],
                           W2[2], W2[3], W2[4]);
    }

    hipLaunchKernelGGL(k1_grads_mf, dim3(1024), dim3(1024), 0, stream,
                       y, ws,
                       b0[0], b1[0], W2[0], b0[1], b1[1], W2[1],
                       ws + OFF_DE, ws + OFF_DS);

    const int k2_smem = 154112;
    if (big4) {
        hipFuncSetAttribute((const void*)k2_poisson_mf2, hipFuncAttributeMaxDynamicSharedMemorySize, k2_smem);
        hipLaunchKernelGGL(k2_poisson_mf2, dim3(1024), dim3(1024), k2_smem, stream,
                           y, ws, b0[2], b1[2], dout);
    } else {
        hipFuncSetAttribute((const void*)k2_poisson_mf, hipFuncAttributeMaxDynamicSharedMemorySize, k2_smem);
        hipLaunchKernelGGL(k2_poisson_mf, dim3(1024), dim3(1024), k2_smem, stream,
                           y, ws, b0[2], b1[2], dout);
    }

    const int k3_smem = 78080;
    hipFuncSetAttribute((const void*)k3_friction_mf4, hipFuncAttributeMaxDynamicSharedMemorySize, k3_smem);
    hipLaunchKernelGGL(k3_friction_mf4, dim3(1024), dim3(1024), k3_smem, stream,
                       y, ws, b0[3], b1[3], b0[4], b1[4], dout);
}

// Round 18
// 521.578 us; speedup vs baseline: 1.9955x; 1.9955x over previous
//
#include <hip/hip_runtime.h>
#include <math.h>

// Problem constants: B=16384 samples, DIM=64, WIDTH=256, DD=64, C2=16
#define SB 16      // samples per workgroup

// ws layout (float offsets)
#define OFF_W0T  0            // 5 x (64x256) (fallback k2_mf only)
#define OFF_W1T  81920        // 5 x (256x256) (fallback k2_mf only)
#define OFF_W2PT 409600       // unused on mf path
#define OFF_W2CT 925696
#define OFF_W2BT 1187840
#define OFF_DE   2236416      // 16384x64
#define OFF_DS   3284992      // 16384x64
#define WS_FLOATS 4337600
#define NPACK  1048576        // W2B packs
#define NPACKC 262144         // W2C packs
#define NPACKP 524288         // W2P packs (padded 2048)
#define WS3_FLOATS (WS_FLOATS + NPACK + NPACKC + NPACKP)
#define NK1 327680            // k1 packs
#define WS4_FLOATS (WS3_FLOATS + NK1)
#define NK3F 163840           // k3 forward packs (fC, fB)
#define WS5_FLOATS (WS4_FLOATS + NK3F)
#define NK2F 81920            // k2 forward packs (pA)
#define WS6_FLOATS (WS5_FLOATS + NK2F)

typedef __attribute__((ext_vector_type(8))) short bf16x8;
typedef __attribute__((ext_vector_type(4))) float f32x4;

__device__ __forceinline__ float4 f4fma(float a, float4 w, float4 c) {
    c.x = fmaf(a, w.x, c.x); c.y = fmaf(a, w.y, c.y);
    c.z = fmaf(a, w.z, c.z); c.w = fmaf(a, w.w, c.w);
    return c;
}

__device__ __forceinline__ float4 tanh4b(float4 a, float b) {
    return make_float4(tanhf(a.x + b), tanhf(a.y + b), tanhf(a.z + b), tanhf(a.w + b));
}

// fp32 -> bf16 hi (RNE) + bf16 lo (RNE of remainder)
__device__ __forceinline__ void bf16split(float x, unsigned short& hi, unsigned short& lo) {
    unsigned b = __float_as_uint(x);
    unsigned h = (b + 0x7FFFu + ((b >> 16) & 1u)) >> 16;
    hi = (unsigned short)h;
    float r = x - __uint_as_float(h << 16);
    unsigned rb = __float_as_uint(r);
    lo = (unsigned short)((rb + 0x7FFFu + ((rb >> 16) & 1u)) >> 16);
}

#define MFMA3(acc, Ah, Al, Bh, Bl)                                            \
    acc = __builtin_amdgcn_mfma_f32_16x16x32_bf16(Ah, Bh, acc, 0, 0, 0);      \
    acc = __builtin_amdgcn_mfma_f32_16x16x32_bf16(Al, Bh, acc, 0, 0, 0);      \
    acc = __builtin_amdgcn_mfma_f32_16x16x32_bf16(Ah, Bl, acc, 0, 0, 0);

// ---------------- merged transpose + bf16 fragment packing ----------------
__global__ __launch_bounds__(1024) void k_transpose_all(
    float* __restrict__ ws, int skipmid, int tofs,
    const float* __restrict__ W0a, const float* __restrict__ W0b, const float* __restrict__ W0c,
    const float* __restrict__ W0d, const float* __restrict__ W0e,
    const float* __restrict__ W1a, const float* __restrict__ W1b, const float* __restrict__ W1c,
    const float* __restrict__ W1d, const float* __restrict__ W1e,
    const float* __restrict__ W2p, const float* __restrict__ W2c, const float* __restrict__ W2b)
{
    int t = blockIdx.x * blockDim.x + threadIdx.x + tofs;
    if (t >= 2236416) {
        int e = t - 2236416;
        unsigned short* PK = (unsigned short*)(ws + WS_FLOATS);
        if (e < NPACK) {
            int j = e & 7, lane = (e >> 3) & 63, c = (e >> 9) & 7, tt = e >> 12;
            int k = c * 32 + ((lane >> 4) & 3) * 8 + j;
            int n = tt * 16 + (lane & 15);
            unsigned short hi, lo;
            bf16split(W2b[n * 256 + k], hi, lo);
            PK[e] = hi; PK[NPACK + e] = lo;
        } else if (e < NPACK + NPACKC) {
            int e2 = e - NPACK;
            unsigned short* PC = PK + 2 * NPACK;
            int j = e2 & 7, lane = (e2 >> 3) & 63, c = (e2 >> 9) & 7, tt = e2 >> 12;
            int k = c * 32 + ((lane >> 4) & 3) * 8 + j;
            int n = tt * 16 + (lane & 15);
            unsigned short hi, lo;
            bf16split(W2c[n * 256 + k], hi, lo);
            PC[e2] = hi; PC[NPACKC + e2] = lo;
        } else if (e < NPACK + NPACKC + NPACKP) {
            int e2 = e - NPACK - NPACKC;
            unsigned short* PP = PK + 2 * NPACK + 2 * NPACKC;
            int j = e2 & 7, lane = (e2 >> 3) & 63, c = (e2 >> 9) & 7, tt = e2 >> 12;
            int k = c * 32 + ((lane >> 4) & 3) * 8 + j;
            int n = tt * 16 + (lane & 15);
            float v = (n < 2016) ? W2p[n * 256 + k] : 0.f;
            unsigned short hi, lo;
            bf16split(v, hi, lo);
            PP[e2] = hi; PP[NPACKP + e2] = lo;
        } else if (e < NPACK + NPACKC + NPACKP + NK1) {
            int e2 = e - NPACK - NPACKC - NPACKP;
            unsigned short* PQ = PK + 2 * (NPACK + NPACKC + NPACKP);
            int net = e2 / 163840;
            int r = e2 - net * 163840;
            const float* W0m = net ? W0b : W0a;
            const float* W1m = net ? W1b : W1a;
            float v;
            if (r < 16384) {
                int j = r & 7, lane = (r >> 3) & 63, cb = (r >> 9) & 1, tt = r >> 10;
                int k = cb * 32 + ((lane >> 4) & 3) * 8 + j;
                int n = tt * 16 + (lane & 15);
                v = W0m[n * 64 + k];
            } else if (r < 81920) {
                int r2 = r - 16384;
                int j = r2 & 7, lane = (r2 >> 3) & 63, cb = (r2 >> 9) & 7, tt = r2 >> 12;
                int k = cb * 32 + ((lane >> 4) & 3) * 8 + j;
                int n = tt * 16 + (lane & 15);
                v = W1m[n * 256 + k];
            } else if (r < 147456) {
                int r2 = r - 81920;
                int j = r2 & 7, lane = (r2 >> 3) & 63, cb = (r2 >> 9) & 7, tt = r2 >> 12;
                int k = cb * 32 + ((lane >> 4) & 3) * 8 + j;
                int n = tt * 16 + (lane & 15);
                v = W1m[k * 256 + n];
            } else {
                int r2 = r - 147456;
                int j = r2 & 7, lane = (r2 >> 3) & 63, cb = (r2 >> 9) & 7, tt = r2 >> 12;
                int k = cb * 32 + ((lane >> 4) & 3) * 8 + j;
                int n = tt * 16 + (lane & 15);
                v = W0m[k * 64 + n];
            }
            unsigned short hi, lo;
            bf16split(v, hi, lo);
            PQ[e2] = hi; PQ[NK1 + e2] = lo;
        } else if (e < NPACK + NPACKC + NPACKP + NK1 + NK3F) {
            int e2 = e - NPACK - NPACKC - NPACKP - NK1;
            unsigned short* PQ = PK + 2 * (NPACK + NPACKC + NPACKP + NK1);
            int net = e2 / 81920;
            int r = e2 - net * 81920;
            const float* W0m = net ? W0e : W0d;
            const float* W1m = net ? W1e : W1d;
            float v;
            if (r < 16384) {
                int j = r & 7, lane = (r >> 3) & 63, cb = (r >> 9) & 1, tt = r >> 10;
                int k = cb * 32 + ((lane >> 4) & 3) * 8 + j;
                int n = tt * 16 + (lane & 15);
                v = W0m[n * 64 + k];
            } else {
                int r2 = r - 16384;
                int j = r2 & 7, lane = (r2 >> 3) & 63, cb = (r2 >> 9) & 7, tt = r2 >> 12;
                int k = cb * 32 + ((lane >> 4) & 3) * 8 + j;
                int n = tt * 16 + (lane & 15);
                v = W1m[n * 256 + k];
            }
            unsigned short hi, lo;
            bf16split(v, hi, lo);
            PQ[e2] = hi; PQ[NK3F + e2] = lo;
        } else if (e < NPACK + NPACKC + NPACKP + NK1 + NK3F + NK2F) {
            int r = e - NPACK - NPACKC - NPACKP - NK1 - NK3F;
            unsigned short* PQ = PK + 2 * (NPACK + NPACKC + NPACKP + NK1 + NK3F);
            float v;
            if (r < 16384) {
                int j = r & 7, lane = (r >> 3) & 63, cb = (r >> 9) & 1, tt = r >> 10;
                int k = cb * 32 + ((lane >> 4) & 3) * 8 + j;
                int n = tt * 16 + (lane & 15);
                v = W0c[n * 64 + k];
            } else {
                int r2 = r - 16384;
                int j = r2 & 7, lane = (r2 >> 3) & 63, cb = (r2 >> 9) & 7, tt = r2 >> 12;
                int k = cb * 32 + ((lane >> 4) & 3) * 8 + j;
                int n = tt * 16 + (lane & 15);
                v = W1c[n * 256 + k];
            }
            unsigned short hi, lo;
            bf16split(v, hi, lo);
            PQ[r] = hi; PQ[NK2F + r] = lo;
        }
        return;
    }
    if (skipmid && t >= 409600) return;
    const float* in;
    int o, R, C;
    float* out;
    if (t < 81920) {
        int m = t >> 14; o = t & 16383;
        const float* W0s[5] = {W0a, W0b, W0c, W0d, W0e};
        in = W0s[m]; out = ws + OFF_W0T + m * 16384; R = 256; C = 64;
    } else if (t < 409600) {
        int t2 = t - 81920;
        int m = t2 >> 16; o = t2 & 65535;
        const float* W1s[5] = {W1a, W1b, W1c, W1d, W1e};
        in = W1s[m]; out = ws + OFF_W1T + m * 65536; R = 256; C = 256;
    } else if (t < 925696) {
        o = t - 409600; in = W2p; out = ws + OFF_W2PT; R = 2016; C = 256;
    } else if (t < 1187840) {
        o = t - 925696; in = W2c; out = ws + OFF_W2CT; R = 1024; C = 256;
    } else {
        o = t - 1187840; in = W2b; out = ws + OFF_W2BT; R = 4096; C = 256;
    }
    int c = o / R, r = o - c * R;
    out[o] = in[r * C + c];
}

// ---------------- K1 mf: all four GEMM passes via split-bf16 MFMA ----------------
__global__ __launch_bounds__(1024, 2) void k1_grads_mf(
    const float* __restrict__ y, const float* __restrict__ ws,
    const float* __restrict__ b0E, const float* __restrict__ b1E, const float* __restrict__ w2E,
    const float* __restrict__ b0S, const float* __restrict__ b1S, const float* __restrict__ w2S,
    float* __restrict__ odE, float* __restrict__ odS)
{
    __shared__ float sH1f[4352];
    __shared__ unsigned short yAh[1024], yAl[1024];
    __shared__ unsigned short bAh[4096], bAl[4096];
    __shared__ unsigned short bBh[4096], bBl[4096];
    __shared__ float sPart[4352];

    const int tid = threadIdx.x;
    const int sbase = blockIdx.x * SB;
    const int wv = tid >> 6, l = tid & 63;

    {
        int s = tid >> 6, k = tid & 63;
        unsigned short hi, lo;
        bf16split(y[sbase * 64 + tid], hi, lo);
        int addr = ((k >> 5) * 64 + (s | (((k >> 3) & 3) << 4))) * 8 + (k & 7);
        yAh[addr] = hi; yAl[addr] = lo;
    }
    __syncthreads();

    const unsigned short* K1H = (const unsigned short*)(ws + WS3_FLOATS);
    const unsigned short* K1L = K1H + NK1;

    for (int m = 0; m < 2; ++m) {
        const float* b0 = m ? b0S : b0E;
        const float* b1 = m ? b1S : b1E;
        const float* w2 = m ? w2S : w2E;
        float* outg = m ? odS : odE;
        const int pbase = m * 163840;

        {
            const unsigned short* PH = K1H + pbase;
            const unsigned short* PL = K1L + pbase;
            f32x4 acc = {0.f, 0.f, 0.f, 0.f};
            #pragma unroll
            for (int cb = 0; cb < 2; ++cb) {
                bf16x8 Ah = *(const bf16x8*)(yAh + (cb * 64 + l) * 8);
                bf16x8 Al = *(const bf16x8*)(yAl + (cb * 64 + l) * 8);
                bf16x8 Bh = *(const bf16x8*)(PH + ((wv * 2 + cb) * 64 + l) * 8);
                bf16x8 Bl = *(const bf16x8*)(PL + ((wv * 2 + cb) * 64 + l) * 8);
                MFMA3(acc, Ah, Al, Bh, Bl);
            }
            int c = 16 * wv + (l & 15);
            float bb = b0[c];
            const int cblk = c >> 5, j0 = c & 7;
            const int lb2 = ((c >> 3) & 3) << 4;
            #pragma unroll
            for (int r = 0; r < 4; ++r) {
                int s = (l >> 4) * 4 + r;
                float h1 = tanhf(acc[r] + bb);
                sH1f[c * 17 + s] = h1;
                unsigned short hi, lo;
                bf16split(h1, hi, lo);
                int base = (cblk * 64 + (s | lb2)) * 8 + j0;
                bBh[base] = hi; bBl[base] = lo;
            }
        }
        __syncthreads();

        {
            const unsigned short* PH = K1H + pbase + 16384;
            const unsigned short* PL = K1L + pbase + 16384;
            f32x4 acc = {0.f, 0.f, 0.f, 0.f};
            #pragma unroll 1
            for (int cb = 0; cb < 8; ++cb) {
                bf16x8 Ah = *(const bf16x8*)(bBh + (cb * 64 + l) * 8);
                bf16x8 Al = *(const bf16x8*)(bBl + (cb * 64 + l) * 8);
                bf16x8 Bh = *(const bf16x8*)(PH + ((wv * 8 + cb) * 64 + l) * 8);
                bf16x8 Bl = *(const bf16x8*)(PL + ((wv * 8 + cb) * 64 + l) * 8);
                MFMA3(acc, Ah, Al, Bh, Bl);
            }
            int c = 16 * wv + (l & 15);
            float bb = b1[c], wvv = w2[c];
            const int cblk = c >> 5, j0 = c & 7;
            const int lb2 = ((c >> 3) & 3) << 4;
            #pragma unroll
            for (int r = 0; r < 4; ++r) {
                int s = (l >> 4) * 4 + r;
                float h2 = tanhf(acc[r] + bb);
                float g2 = (1.f - h2 * h2) * wvv;
                unsigned short hi, lo;
                bf16split(g2, hi, lo);
                int base = (cblk * 64 + (s | lb2)) * 8 + j0;
                bAh[base] = hi; bAl[base] = lo;
            }
        }
        __syncthreads();

        {
            const unsigned short* PH = K1H + pbase + 81920;
            const unsigned short* PL = K1L + pbase + 81920;
            f32x4 acc = {0.f, 0.f, 0.f, 0.f};
            #pragma unroll 1
            for (int cb = 0; cb < 8; ++cb) {
                bf16x8 Ah = *(const bf16x8*)(bAh + (cb * 64 + l) * 8);
                bf16x8 Al = *(const bf16x8*)(bAl + (cb * 64 + l) * 8);
                bf16x8 Bh = *(const bf16x8*)(PH + ((wv * 8 + cb) * 64 + l) * 8);
                bf16x8 Bl = *(const bf16x8*)(PL + ((wv * 8 + cb) * 64 + l) * 8);
                MFMA3(acc, Ah, Al, Bh, Bl);
            }
            int c = 16 * wv + (l & 15);
            const int cblk = c >> 5, j0 = c & 7;
            const int lb2 = ((c >> 3) & 3) << 4;
            #pragma unroll
            for (int r = 0; r < 4; ++r) {
                int s = (l >> 4) * 4 + r;
                float h1 = sH1f[c * 17 + s];
                float g1 = (1.f - h1 * h1) * acc[r];
                unsigned short hi, lo;
                bf16split(g1, hi, lo);
                int base = (cblk * 64 + (s | lb2)) * 8 + j0;
                bBh[base] = hi; bBl[base] = lo;
            }
        }
        __syncthreads();

        {
            const unsigned short* PH = K1H + pbase + 147456;
            const unsigned short* PL = K1L + pbase + 147456;
            const int t = wv & 3, kh = wv >> 2;
            f32x4 acc = {0.f, 0.f, 0.f, 0.f};
            #pragma unroll
            for (int q = 0; q < 2; ++q) {
                int cb = 2 * kh + q;
                bf16x8 Ah = *(const bf16x8*)(bBh + (cb * 64 + l) * 8);
                bf16x8 Al = *(const bf16x8*)(bBl + (cb * 64 + l) * 8);
                bf16x8 Bh = *(const bf16x8*)(PH + ((t * 8 + cb) * 64 + l) * 8);
                bf16x8 Bl = *(const bf16x8*)(PL + ((t * 8 + cb) * 64 + l) * 8);
                MFMA3(acc, Ah, Al, Bh, Bl);
            }
            #pragma unroll
            for (int r = 0; r < 4; ++r)
                sPart[(kh * 4 + t) * 272 + (l & 15) * 17 + ((l >> 4) * 4 + r)] = acc[r];
        }
        __syncthreads();
        {
            int s = tid >> 6, i = tid & 63;
            float v = 0.f;
            #pragma unroll
            for (int kh = 0; kh < 4; ++kh)
                v += sPart[(kh * 4 + (i >> 4)) * 272 + (i & 15) * 17 + s];
            outg[sbase * 64 + tid] = v;
        }
        __syncthreads();
    }
}

// ---------------- K2 mf (fallback): forwards fp32, a-GEMM MFMA ----------------
__global__ __launch_bounds__(1024, 4) void k2_poisson_mf(
    const float* __restrict__ y, const float* __restrict__ ws,
    const float* __restrict__ b0P, const float* __restrict__ b1P,
    float* __restrict__ dout)
{
    extern __shared__ float smem[];
    float* sa   = smem;
    unsigned short* sAh = (unsigned short*)(smem + 32384);
    unsigned short* sAl = (unsigned short*)(smem + 34432);
    float* sdE  = smem + 36480;
    float* sdS  = sdE + 1024;
    float* sH1T = sa;
    float* syT  = sa + 4096;

    const int tid = threadIdx.x;
    const int sbase = blockIdx.x * SB;
    const float* gdE = ws + OFF_DE;
    const float* gdS = ws + OFF_DS;

    {
        int s = tid >> 6, i = tid & 63;
        syT[i * 16 + s] = y[sbase * 64 + tid];
        sdE[tid] = gdE[sbase * 64 + tid];
        sdS[tid] = gdS[sbase * 64 + tid];
    }
    __syncthreads();

    const int c  = tid & 255;
    const int sg = tid >> 8;
    const int s4 = sg * 4;

    {
        const float* w0t = ws + OFF_W0T + 2 * 16384;
        float4 acc = {0, 0, 0, 0};
        #pragma unroll 4
        for (int k = 0; k < 64; ++k) {
            float w = w0t[k * 256 + c];
            float4 yv = *(const float4*)(syT + k * 16 + s4);
            acc = f4fma(w, yv, acc);
        }
        *(float4*)(sH1T + c * 16 + s4) = tanh4b(acc, b0P[c]);
    }
    __syncthreads();

    {
        const float* w1t = ws + OFF_W1T + 2 * 65536;
        float4 acc = {0, 0, 0, 0};
        #pragma unroll 4
        for (int k = 0; k < 256; ++k) {
            float w = w1t[k * 256 + c];
            float4 hv = *(const float4*)(sH1T + k * 16 + s4);
            acc = f4fma(w, hv, acc);
        }
        float4 h2 = tanh4b(acc, b1P[c]);
        const int cblk = c >> 5, j0 = c & 7;
        const int lbase = ((c >> 3) & 3) << 4;
        float va[4] = {h2.x, h2.y, h2.z, h2.w};
        #pragma unroll
        for (int q = 0; q < 4; ++q) {
            int lb = ((s4 + q) & 15) | lbase;
            int base = (cblk * 64 + lb) * 8 + j0;
            unsigned short hi, lo;
            bf16split(va[q], hi, lo);
            sAh[base] = hi;
            sAl[base] = lo;
        }
    }
    __syncthreads();

    {
        const unsigned short* PP = (const unsigned short*)(ws + WS_FLOATS) + 2 * NPACK + 2 * NPACKC;
        const unsigned short* PH = PP;
        const unsigned short* PL = PP + NPACKP;
        const int wv = tid >> 6, l = tid & 63;
        f32x4 accp[8];
        #pragma unroll
        for (int t0 = 0; t0 < 8; ++t0) accp[t0] = (f32x4){0.f, 0.f, 0.f, 0.f};
        #pragma unroll 1
        for (int cb = 0; cb < 8; ++cb) {
            bf16x8 Ah = *(const bf16x8*)(sAh + (cb * 64 + l) * 8);
            bf16x8 Al = *(const bf16x8*)(sAl + (cb * 64 + l) * 8);
            #pragma unroll
            for (int t0 = 0; t0 < 8; ++t0) {
                int t = 8 * wv + t0;
                bf16x8 Bh = *(const bf16x8*)(PH + ((t * 8 + cb) * 64 + l) * 8);
                bf16x8 Bl = *(const bf16x8*)(PL + ((t * 8 + cb) * 64 + l) * 8);
                MFMA3(accp[t0], Ah, Al, Bh, Bl);
            }
        }
        #pragma unroll
        for (int t0 = 0; t0 < 8; ++t0) {
            int n = (8 * wv + t0) * 16 + (l & 15);
            if (n < 2016) {
                #pragma unroll
                for (int r = 0; r < 4; ++r)
                    sa[((l >> 4) * 4 + r) * 2024 + n] = accp[t0][r];
            }
        }
    }
    __syncthreads();

    {
        const int s = tid >> 6;
        const int i = tid & 63;
        const int ib = i * (i - 1) / 2;
        const float* ap = sa + s * 2024;
        const float* dep = sdE + s * 64;
        const float* dsp = sdS + s * 64;

        float adE = 0.f, adS = 0.f;
        int trij = 0;
        #pragma unroll 4
        for (int j = 0; j < 64; ++j) {
            int t = (j < i) ? (ib + j) : (trij + i);
            float sel = (j < i) ? 1.f : ((j == i) ? 0.f : -1.f);
            float cc = sel * ap[t];
            adE = fmaf(cc, dep[j], adE);
            adS = fmaf(cc, dsp[j], adS);
            trij += j;
        }

        float de = dep[i], dsv = dsp[i];
        float p0 = de * adS;
        float p1 = de * dsv;
        float p2 = dsv * dsv;
        #pragma unroll
        for (int m = 1; m <= 32; m <<= 1) {
            p0 += __shfl_xor(p0, m);
            p1 += __shfl_xor(p1, m);
            p2 += __shfl_xor(p2, m);
        }
        float inv = 1.f / p2;
        dout[sbase * 64 + tid] = adE + (p0 * dsv - p1 * adS) * inv;
    }
}

// ---------------- K2 mf2: forwards AND a-GEMM via split-bf16 MFMA ----------------
__global__ __launch_bounds__(1024, 4) void k2_poisson_mf2(
    const float* __restrict__ y, const float* __restrict__ ws,
    const float* __restrict__ b0P, const float* __restrict__ b1P,
    float* __restrict__ dout)
{
    extern __shared__ float smem[];
    float* sa   = smem;                                   // 16 x 2024
    unsigned short* yAh = (unsigned short*)(smem);
    unsigned short* yAl = (unsigned short*)(smem + 512);
    unsigned short* h1H = (unsigned short*)(smem + 1024);
    unsigned short* h1L = (unsigned short*)(smem + 3072);
    unsigned short* sAh = (unsigned short*)(smem + 32384);
    unsigned short* sAl = (unsigned short*)(smem + 34432);
    float* sdE  = smem + 36480;
    float* sdS  = sdE + 1024;

    const int tid = threadIdx.x;
    const int sbase = blockIdx.x * SB;
    const float* gdE = ws + OFF_DE;
    const float* gdS = ws + OFF_DS;

    {
        int s = tid >> 6, k = tid & 63;
        unsigned short hi, lo;
        bf16split(y[sbase * 64 + tid], hi, lo);
        int addr = ((k >> 5) * 64 + (s | (((k >> 3) & 3) << 4))) * 8 + (k & 7);
        yAh[addr] = hi; yAl[addr] = lo;
        sdE[tid] = gdE[sbase * 64 + tid];
        sdS[tid] = gdS[sbase * 64 + tid];
    }
    __syncthreads();

    const int wv = tid >> 6, l = tid & 63;
    const unsigned short* F2H = (const unsigned short*)(ws + WS5_FLOATS);
    const unsigned short* F2L = F2H + NK2F;

    {
        f32x4 acc = {0.f, 0.f, 0.f, 0.f};
        #pragma unroll
        for (int cb = 0; cb < 2; ++cb) {
            bf16x8 Ah = *(const bf16x8*)(yAh + (cb * 64 + l) * 8);
            bf16x8 Al = *(const bf16x8*)(yAl + (cb * 64 + l) * 8);
            bf16x8 Bh = *(const bf16x8*)(F2H + ((wv * 2 + cb) * 64 + l) * 8);
            bf16x8 Bl = *(const bf16x8*)(F2L + ((wv * 2 + cb) * 64 + l) * 8);
            MFMA3(acc, Ah, Al, Bh, Bl);
        }
        int c = 16 * wv + (l & 15);
        float bb = b0P[c];
        const int cblk = c >> 5, j0 = c & 7;
        const int lb2 = ((c >> 3) & 3) << 4;
        #pragma unroll
        for (int r = 0; r < 4; ++r) {
            int s = (l >> 4) * 4 + r;
            float h1 = tanhf(acc[r] + bb);
            unsigned short hi, lo;
            bf16split(h1, hi, lo);
            int base = (cblk * 64 + (s | lb2)) * 8 + j0;
            h1H[base] = hi; h1L[base] = lo;
        }
    }
    __syncthreads();

    {
        f32x4 acc = {0.f, 0.f, 0.f, 0.f};
        #pragma unroll 1
        for (int cb = 0; cb < 8; ++cb) {
            bf16x8 Ah = *(const bf16x8*)(h1H + (cb * 64 + l) * 8);
            bf16x8 Al = *(const bf16x8*)(h1L + (cb * 64 + l) * 8);
            bf16x8 Bh = *(const bf16x8*)(F2H + 16384 + ((wv * 8 + cb) * 64 + l) * 8);
            bf16x8 Bl = *(const bf16x8*)(F2L + 16384 + ((wv * 8 + cb) * 64 + l) * 8);
            MFMA3(acc, Ah, Al, Bh, Bl);
        }
        int c = 16 * wv + (l & 15);
        float bb = b1P[c];
        const int cblk = c >> 5, j0 = c & 7;
        const int lb2 = ((c >> 3) & 3) << 4;
        #pragma unroll
        for (int r = 0; r < 4; ++r) {
            int s = (l >> 4) * 4 + r;
            float h2 = tanhf(acc[r] + bb);
            unsigned short hi, lo;
            bf16split(h2, hi, lo);
            int base = (cblk * 64 + (s | lb2)) * 8 + j0;
            sAh[base] = hi; sAl[base] = lo;
        }
    }
    __syncthreads();

    {
        const unsigned short* PP = (const unsigned short*)(ws + WS_FLOATS) + 2 * NPACK + 2 * NPACKC;
        const unsigned short* PH = PP;
        const unsigned short* PL = PP + NPACKP;
        f32x4 accp[8];
        #pragma unroll
        for (int t0 = 0; t0 < 8; ++t0) accp[t0] = (f32x4){0.f, 0.f, 0.f, 0.f};
        #pragma unroll 1
        for (int cb = 0; cb < 8; ++cb) {
            bf16x8 Ah = *(const bf16x8*)(sAh + (cb * 64 + l) * 8);
            bf16x8 Al = *(const bf16x8*)(sAl + (cb * 64 + l) * 8);
            #pragma unroll
            for (int t0 = 0; t0 < 8; ++t0) {
                int t = 8 * wv + t0;
                bf16x8 Bh = *(const bf16x8*)(PH + ((t * 8 + cb) * 64 + l) * 8);
                bf16x8 Bl = *(const bf16x8*)(PL + ((t * 8 + cb) * 64 + l) * 8);
                MFMA3(accp[t0], Ah, Al, Bh, Bl);
            }
        }
        #pragma unroll
        for (int t0 = 0; t0 < 8; ++t0) {
            int n = (8 * wv + t0) * 16 + (l & 15);
            if (n < 2016) {
                #pragma unroll
                for (int r = 0; r < 4; ++r)
                    sa[((l >> 4) * 4 + r) * 2024 + n] = accp[t0][r];
            }
        }
    }
    __syncthreads();

    {
        const int s = tid >> 6;
        const int i = tid & 63;
        const int ib = i * (i - 1) / 2;
        const float* ap = sa + s * 2024;
        const float* dep = sdE + s * 64;
        const float* dsp = sdS + s * 64;

        float adE = 0.f, adS = 0.f;
        int trij = 0;
        #pragma unroll 4
        for (int j = 0; j < 64; ++j) {
            int t = (j < i) ? (ib + j) : (trij + i);
            float sel = (j < i) ? 1.f : ((j == i) ? 0.f : -1.f);
            float cc = sel * ap[t];
            adE = fmaf(cc, dep[j], adE);
            adS = fmaf(cc, dsp[j], adS);
            trij += j;
        }

        float de = dep[i], dsv = dsp[i];
        float p0 = de * adS;
        float p1 = de * dsv;
        float p2 = dsv * dsv;
        #pragma unroll
        for (int m = 1; m <= 32; m <<= 1) {
            p0 += __shfl_xor(p0, m);
            p1 += __shfl_xor(p1, m);
            p2 += __shfl_xor(p2, m);
        }
        float inv = 1.f / p2;
        dout[sbase * 64 + tid] = adE + (p0 * dsv - p1 * adS) * inv;
    }
}

// ---------------- K3 mf3: forwards AND C AND Bm via split-bf16 MFMA (proven R15/R16) ----------------
__global__ __launch_bounds__(1024, 4) void k3_friction_mf3(
    const float* __restrict__ y, const float* __restrict__ ws,
    const float* __restrict__ b0C, const float* __restrict__ b1C,
    const float* __restrict__ b0B, const float* __restrict__ b1B,
    float* __restrict__ dout)
{
    extern __shared__ float smem[];
    unsigned short* yAh = (unsigned short*)(smem);
    unsigned short* yAl = (unsigned short*)(smem + 512);
    unsigned short* sAhc = (unsigned short*)(smem + 1024);
    unsigned short* sAlc = (unsigned short*)(smem + 3072);
    unsigned short* sAhb = (unsigned short*)(smem + 5120);
    unsigned short* sAlb = (unsigned short*)(smem + 7168);
    unsigned short* h1ch = (unsigned short*)(smem + 9216);
    unsigned short* h1cl = (unsigned short*)(smem + 11264);
    unsigned short* h1bh = (unsigned short*)(smem + 13312);
    unsigned short* h1bl = (unsigned short*)(smem + 15360);
    float* sC   = smem + 9216;
    float* sdE  = smem + 26640;
    float* sdS  = smem + 27664;
    float* sBdE = smem + 28688;
    float* sBdS = smem + 29712;
    float* sv   = smem + 30736;
    float* sq   = smem + 31760;
    float* sScal= smem + 32784;
    float* sr   = smem + 32848;

    const int tid = threadIdx.x;
    const int sbase = blockIdx.x * SB;
    const float* gdE = ws + OFF_DE;
    const float* gdS = ws + OFF_DS;

    {
        int s = tid >> 6, k = tid & 63;
        unsigned short hi, lo;
        bf16split(y[sbase * 64 + tid], hi, lo);
        int addr = ((k >> 5) * 64 + (s | (((k >> 3) & 3) << 4))) * 8 + (k & 7);
        yAh[addr] = hi; yAl[addr] = lo;
        sdE[tid] = gdE[sbase * 64 + tid];
        sdS[tid] = gdS[sbase * 64 + tid];
    }
    if (tid < 64) sScal[tid] = 0.f;
    __syncthreads();

    {
        int s = tid >> 6;
        float de = sdE[tid];
        unsafeAtomicAdd(&sScal[s * 4 + 0], de * de);
        unsafeAtomicAdd(&sScal[s * 4 + 1], de * sdS[tid]);
    }

    const int wv = tid >> 6;
    const int l  = tid & 63;
    const int netw = wv >> 3;
    const int tb   = wv & 7;
    const float* b0v = netw ? b0B : b0C;
    const float* b1v = netw ? b1B : b1C;
    unsigned short* h1H = netw ? h1bh : h1ch;
    unsigned short* h1L = netw ? h1bl : h1cl;
    unsigned short* h2H = netw ? sAhb : sAhc;
    unsigned short* h2L = netw ? sAlb : sAlc;

    const unsigned short* F3H = (const unsigned short*)(ws + WS4_FLOATS);
    const unsigned short* F3L = F3H + NK3F;

    #pragma unroll
    for (int jj = 0; jj < 2; ++jj) {
        int t = tb + 8 * jj;
        f32x4 acc = {0.f, 0.f, 0.f, 0.f};
        #pragma unroll
        for (int cb = 0; cb < 2; ++cb) {
            bf16x8 Ah = *(const bf16x8*)(yAh + (cb * 64 + l) * 8);
            bf16x8 Al = *(const bf16x8*)(yAl + (cb * 64 + l) * 8);
            const unsigned short* bh = F3H + netw * 81920 + ((t * 2 + cb) * 64 + l) * 8;
            const unsigned short* bl = F3L + netw * 81920 + ((t * 2 + cb) * 64 + l) * 8;
            bf16x8 Bh = *(const bf16x8*)(bh);
            bf16x8 Bl = *(const bf16x8*)(bl);
            MFMA3(acc, Ah, Al, Bh, Bl);
        }
        int c = 16 * t + (l & 15);
        float bb = b0v[c];
        const int cblk = c >> 5, j0 = c & 7;
        const int lb2 = ((c >> 3) & 3) << 4;
        #pragma unroll
        for (int r = 0; r < 4; ++r) {
            int s = (l >> 4) * 4 + r;
            float h1 = tanhf(acc[r] + bb);
            unsigned short hi, lo;
            bf16split(h1, hi, lo);
            int base = (cblk * 64 + (s | lb2)) * 8 + j0;
            h1H[base] = hi; h1L[base] = lo;
        }
    }
    __syncthreads();

    #pragma unroll
    for (int jj = 0; jj < 2; ++jj) {
        int t = tb + 8 * jj;
        f32x4 acc = {0.f, 0.f, 0.f, 0.f};
        #pragma unroll 1
        for (int cb = 0; cb < 8; ++cb) {
            bf16x8 Ah = *(const bf16x8*)(h1H + (cb * 64 + l) * 8);
            bf16x8 Al = *(const bf16x8*)(h1L + (cb * 64 + l) * 8);
            const unsigned short* bh = F3H + netw * 81920 + 16384 + ((t * 8 + cb) * 64 + l) * 8;
            const unsigned short* bl = F3L + netw * 81920 + 16384 + ((t * 8 + cb) * 64 + l) * 8;
            bf16x8 Bh = *(const bf16x8*)(bh);
            bf16x8 Bl = *(const bf16x8*)(bl);
            MFMA3(acc, Ah, Al, Bh, Bl);
        }
        int c = 16 * t + (l & 15);
        float bb = b1v[c];
        const int cblk = c >> 5, j0 = c & 7;
        const int lb2 = ((c >> 3) & 3) << 4;
        #pragma unroll
        for (int r = 0; r < 4; ++r) {
            int s = (l >> 4) * 4 + r;
            float h2 = tanhf(acc[r] + bb);
            unsigned short hi, lo;
            bf16split(h2, hi, lo);
            int base = (cblk * 64 + (s | lb2)) * 8 + j0;
            h2H[base] = hi; h2L[base] = lo;
        }
    }
    __syncthreads();

    {
        const unsigned short* PC = (const unsigned short*)(ws + WS_FLOATS) + 2 * NPACK;
        const unsigned short* CH = PC;
        const unsigned short* CL = PC + NPACKC;
        f32x4 accc[4];
        #pragma unroll
        for (int t0 = 0; t0 < 4; ++t0) accc[t0] = (f32x4){0.f, 0.f, 0.f, 0.f};
        #pragma unroll 1
        for (int cb = 0; cb < 8; ++cb) {
            bf16x8 Ah = *(const bf16x8*)(sAhc + (cb * 64 + l) * 8);
            bf16x8 Al = *(const bf16x8*)(sAlc + (cb * 64 + l) * 8);
            #pragma unroll
            for (int t0 = 0; t0 < 4; ++t0) {
                int t = 4 * wv + t0;
                bf16x8 Bh = *(const bf16x8*)(CH + ((t * 8 + cb) * 64 + l) * 8);
                bf16x8 Bl = *(const bf16x8*)(CL + ((t * 8 + cb) * 64 + l) * 8);
                MFMA3(accc[t0], Ah, Al, Bh, Bl);
            }
        }
        #pragma unroll
        for (int t0 = 0; t0 < 4; ++t0) {
            int t = 4 * wv + t0;
            #pragma unroll
            for (int r = 0; r < 4; ++r)
                sC[((l >> 4) * 4 + r) * 1089 + t * 17 + (l & 15)] = accc[t0][r];
        }
    }

    f32x4 acc[16];
    #pragma unroll
    for (int t0 = 0; t0 < 16; ++t0) acc[t0] = (f32x4){0.f, 0.f, 0.f, 0.f};
    {
        const unsigned short* BH = (const unsigned short*)(ws + WS_FLOATS);
        const unsigned short* BL = BH + NPACK;
        #pragma unroll 1
        for (int cb = 0; cb < 8; ++cb) {
            bf16x8 Ah = *(const bf16x8*)(sAhb + (cb * 64 + l) * 8);
            bf16x8 Al = *(const bf16x8*)(sAlb + (cb * 64 + l) * 8);
            const unsigned short* bh = BH + ((wv * 16 * 8 + cb) * 64 + l) * 8;
            const unsigned short* bl = BL + ((wv * 16 * 8 + cb) * 64 + l) * 8;
            #pragma unroll
            for (int t0 = 0; t0 < 16; ++t0) {
                bf16x8 Bh = *(const bf16x8*)(bh + t0 * 4096);
                bf16x8 Bl = *(const bf16x8*)(bl + t0 * 4096);
                MFMA3(acc[t0], Ah, Al, Bh, Bl);
            }
        }
    }
    #pragma unroll
    for (int g = 0; g < 4; ++g) {
        float pd[4] = {0, 0, 0, 0}, ps[4] = {0, 0, 0, 0};
        #pragma unroll
        for (int tt = 0; tt < 4; ++tt) {
            int i = 16 * tt + (l & 15);
            #pragma unroll
            for (int r = 0; r < 4; ++r) {
                int s = (l >> 4) * 4 + r;
                float d = acc[g * 4 + tt][r];
                pd[r] = fmaf(d, sdE[s * 64 + i], pd[r]);
                ps[r] = fmaf(d, sdS[s * 64 + i], ps[r]);
            }
        }
        #pragma unroll
        for (int m = 1; m <= 8; m <<= 1) {
            #pragma unroll
            for (int r = 0; r < 4; ++r) {
                pd[r] += __shfl_xor(pd[r], m);
                ps[r] += __shfl_xor(ps[r], m);
            }
        }
        if ((l & 15) == 0) {
            int kpr = 4 * wv + g;
            #pragma unroll
            for (int r = 0; r < 4; ++r) {
                int s = (l >> 4) * 4 + r;
                sBdE[s * 64 + kpr] = pd[r];
                sBdS[s * 64 + kpr] = ps[r];
            }
        }
    }
    __syncthreads();

    {
        int s = tid >> 6;
        float beta = sScal[s * 4 + 1] / sScal[s * 4 + 0];
        sv[tid] = sBdS[tid] - beta * sBdE[tid];
    }
    __syncthreads();
    {
        int s = tid >> 6;
        unsafeAtomicAdd(&sScal[s * 4 + 2], sdE[tid] * sv[tid]);
    }
    __syncthreads();

    #pragma unroll
    for (int g = 0; g < 4; ++g) {
        float pq[4] = {0, 0, 0, 0};
        #pragma unroll
        for (int tt = 0; tt < 4; ++tt) {
            int i = 16 * tt + (l & 15);
            #pragma unroll
            for (int r = 0; r < 4; ++r) {
                int s = (l >> 4) * 4 + r;
                pq[r] = fmaf(acc[g * 4 + tt][r], sv[s * 64 + i], pq[r]);
            }
        }
        #pragma unroll
        for (int m = 1; m <= 8; m <<= 1) {
            #pragma unroll
            for (int r = 0; r < 4; ++r) pq[r] += __shfl_xor(pq[r], m);
        }
        if ((l & 15) == 0) {
            int kpr = 4 * wv + g;
            #pragma unroll
            for (int r = 0; r < 4; ++r) sq[((l >> 4) * 4 + r) * 64 + kpr] = pq[r];
        }
    }
    __syncthreads();

    if (tid < 256) {
        int s = tid >> 4, m = tid & 15;
        float gamma = sScal[s * 4 + 2] / sScal[s * 4 + 0];
        float r = 0.f;
        #pragma unroll 4
        for (int k = 0; k < 64; ++k) {
            float wvv = sq[s * 64 + k] - gamma * sBdE[s * 64 + k];
            r = fmaf(sC[s * 1089 + k * 17 + m], wvv, r);
        }
        sr[s * 16 + m] = r;
    }
    __syncthreads();
    {
        int s = tid >> 6, k = tid & 63;
        float o = 0.f;
        #pragma unroll
        for (int m2 = 0; m2 < 16; ++m2)
            o = fmaf(sC[s * 1089 + k * 17 + m2], sr[s * 16 + m2], o);
        int gi = sbase * 64 + tid;
        dout[gi] = dout[gi] + o;
    }
}

extern "C" void kernel_launch(void* const* d_in, const int* in_sizes, int n_in,
                              void* d_out, int out_size, void* d_ws, size_t ws_size,
                              hipStream_t stream)
{
    (void)in_sizes; (void)n_in; (void)out_size;
    const float* y = (const float*)d_in[1];
    const float* W0[5]; const float* b0[5]; const float* W1[5]; const float* b1[5]; const float* W2[5];
    for (int m = 0; m < 5; ++m) {
        int base = 2 + m * 5;
        W0[m] = (const float*)d_in[base + 0];
        b0[m] = (const float*)d_in[base + 1];
        W1[m] = (const float*)d_in[base + 2];
        b1[m] = (const float*)d_in[base + 3];
        W2[m] = (const float*)d_in[base + 4];
    }
    float* ws = (float*)d_ws;
    float* dout = (float*)d_out;
    if (ws_size < (size_t)WS5_FLOATS * sizeof(float)) return;
    const bool big4 = ws_size >= (size_t)WS6_FLOATS * sizeof(float);

    if (big4) {
        // mf path reads only the pack segments; skip all fp32 transposes
        const int npack_all = NPACK + NPACKC + NPACKP + NK1 + NK3F + NK2F;
        hipLaunchKernelGGL(k_transpose_all, dim3((npack_all + 1023) / 1024), dim3(1024), 0, stream,
                           ws, 1, 2236416,
                           W0[0], W0[1], W0[2], W0[3], W0[4],
                           W1[0], W1[1], W1[2], W1[3], W1[4],
                           W2[2], W2[3], W2[4]);
    } else {
        const int ntr = 2236416 + NPACK + NPACKC + NPACKP + NK1 + NK3F;
        hipLaunchKernelGGL(k_transpose_all, dim3((ntr + 1023) / 1024), dim3(1024), 0, stream,
                           ws, 1, 0,
                           W0[0], W0[1], W0[2], W0[3], W0[4],
                           W1[0], W1[1], W1[2], W1[3], W1[4],
                           W2[2], W2[3], W2[4]);
    }

    hipLaunchKernelGGL(k1_grads_mf, dim3(1024), dim3(1024), 0, stream,
                       y, ws,
                       b0[0], b1[0], W2[0], b0[1], b1[1], W2[1],
                       ws + OFF_DE, ws + OFF_DS);

    const int k2_smem = 154112;
    if (big4) {
        hipFuncSetAttribute((const void*)k2_poisson_mf2, hipFuncAttributeMaxDynamicSharedMemorySize, k2_smem);
        hipLaunchKernelGGL(k2_poisson_mf2, dim3(1024), dim3(1024), k2_smem, stream,
                           y, ws, b0[2], b1[2], dout);
    } else {
        hipFuncSetAttribute((const void*)k2_poisson_mf, hipFuncAttributeMaxDynamicSharedMemorySize, k2_smem);
        hipLaunchKernelGGL(k2_poisson_mf, dim3(1024), dim3(1024), k2_smem, stream,
                           y, ws, b0[2], b1[2], dout);
    }

    const int k3_smem = 132416;
    hipFuncSetAttribute((const void*)k3_friction_mf3, hipFuncAttributeMaxDynamicSharedMemorySize, k3_smem);
    hipLaunchKernelGGL(k3_friction_mf3, dim3(1024), dim3(1024), k3_smem, stream,
                       y, ws, b0[3], b1[3], b0[4], b1[4], dout);
}